// Round 2
// baseline (14208.156 us; speedup 1.0000x reference)
//
#include <hip/hip_runtime.h>
#include <hip/hip_bf16.h>
#include <stdint.h>

#define TT 512
#define BB 32
#define II 256
#define HH 512
#define OO 256
#define N4H 2048

typedef __attribute__((ext_vector_type(8))) short bf16x8;
typedef __attribute__((ext_vector_type(4))) float f32x4;

static __device__ __forceinline__ f32x4 MFMA(bf16x8 a, bf16x8 b, f32x4 c) {
  return __builtin_amdgcn_mfma_f32_16x16x32_bf16(a, b, c, 0, 0, 0);
}
static __device__ __forceinline__ unsigned short f2bf(float x) {
  union { float f; unsigned u; } v; v.f = x;
  unsigned r = v.u + 0x7FFFu + ((v.u >> 16) & 1u);
  return (unsigned short)(r >> 16);
}
static __device__ __forceinline__ float bf2f(unsigned short b) {
  union { unsigned u; float f; } v; v.u = ((unsigned)b) << 16; return v.f;
}
static __device__ __forceinline__ float sigm(float x) {
  return 1.0f / (1.0f + __expf(-x));
}
static __device__ __forceinline__ float tanh_(float x) {
  return 1.0f - 2.0f / (1.0f + __expf(2.0f * x));
}

// ---------------- prep kernels ----------------

// Split-convert row-major f32 [rows][K] into col-major bf16 hi/lo [N][K].
// packed: col c <- src row (c&3)*HH + (c>>2)  (i,f,g,o interleaved per unit)
__global__ void prep_w(const float* __restrict__ src, unsigned short* __restrict__ hi,
                       unsigned short* __restrict__ lo, int K, int N, int packed) {
  int tid = blockIdx.x * 256 + threadIdx.x;
  int nch = K >> 3;
  if (tid >= N * nch) return;
  int c = tid / nch;
  int j = (tid - c * nch) << 3;
  int row = packed ? ((c & 3) * HH + (c >> 2)) : c;
  const float* s = src + (size_t)row * K + j;
  alignas(16) unsigned short h8[8];
  alignas(16) unsigned short l8[8];
#pragma unroll
  for (int e = 0; e < 8; ++e) {
    float v = s[e];
    unsigned short hb = f2bf(v);
    h8[e] = hb;
    l8[e] = f2bf(v - bf2f(hb));
  }
  *(uint4*)(hi + (size_t)c * K + j) = *(const uint4*)h8;
  *(uint4*)(lo + (size_t)c * K + j) = *(const uint4*)l8;
}

__global__ void prep_bias(const float* __restrict__ bi0, const float* __restrict__ bh0,
                          const float* __restrict__ bim, const float* __restrict__ bhm,
                          float* __restrict__ bias0p, float* __restrict__ biasmp) {
  int c = blockIdx.x * 256 + threadIdx.x;
  if (c >= N4H) return;
  int row = (c & 3) * HH + (c >> 2);
  bias0p[c] = bi0[row] + bh0[row];
  biasmp[c] = bim[row] + bhm[row];
}

// inputs [B][T][I] f32 -> xb [(t*32+b)][I] bf16
__global__ void prep_x(const float* __restrict__ in, unsigned short* __restrict__ xb) {
  int tid = blockIdx.x * 256 + threadIdx.x;
  if (tid >= 16384 * 32) return;
  int row = tid >> 5, j = (tid & 31) << 3;
  int t = row >> 5, b = row & 31;
  const float* s = in + ((size_t)b * TT + t) * II + j;
  alignas(16) unsigned short o8[8];
#pragma unroll
  for (int e = 0; e < 8; ++e) o8[e] = f2bf(s[e]);
  *(uint4*)(xb + (size_t)row * II + j) = *(const uint4*)o8;
}

// ---------------- big GEMMs ----------------

// gates0_x[16384][2048] = xb @ Wih_in^T (hi+lo) + bias0p   (cols packed u*4+g)
__global__ __launch_bounds__(256) void gemm_g0(
    const unsigned short* __restrict__ A, const unsigned short* __restrict__ Bhi,
    const unsigned short* __restrict__ Blo, const float* __restrict__ biasp,
    float* __restrict__ out) {
  const int K = II;
  int wgm = blockIdx.x & 255;
  int wgn = blockIdx.x >> 8;
  int l = threadIdx.x & 63, wave = threadIdx.x >> 6;
  int mbase = wgm * 64 + wave * 16;
  int nbase = wgn * 64;
  int arow = mbase + (l & 15);
  int koff = (l >> 4) * 8;
  f32x4 acc[4] = {};
  for (int kt = 0; kt < K / 32; ++kt) {
    bf16x8 a = *(const bf16x8*)(A + (size_t)arow * K + kt * 32 + koff);
#pragma unroll
    for (int n = 0; n < 4; ++n) {
      int col = nbase + n * 16 + (l & 15);
      bf16x8 bh = *(const bf16x8*)(Bhi + (size_t)col * K + kt * 32 + koff);
      bf16x8 bl = *(const bf16x8*)(Blo + (size_t)col * K + kt * 32 + koff);
      acc[n] = MFMA(a, bh, acc[n]);
      acc[n] = MFMA(a, bl, acc[n]);
    }
  }
#pragma unroll
  for (int n = 0; n < 4; ++n) {
    int col = nbase + n * 16 + (l & 15);
    float bv = biasp[col];
#pragma unroll
    for (int r = 0; r < 4; ++r) {
      int row = mbase + (l >> 4) * 4 + r;
      out[(size_t)row * N4H + col] = acc[n][r] + bv;
    }
  }
}

// y[b][t][o] = out1 @ fc_w^T (hi+lo) + fc_b
__global__ __launch_bounds__(256) void gemm_fc(
    const unsigned short* __restrict__ A, const unsigned short* __restrict__ Bhi,
    const unsigned short* __restrict__ Blo, const float* __restrict__ bias,
    float* __restrict__ y) {
  const int K = 2 * HH;
  int wgm = blockIdx.x & 255;
  int wgn = blockIdx.x >> 8;
  int l = threadIdx.x & 63, wave = threadIdx.x >> 6;
  int mbase = wgm * 64 + wave * 16;
  int nbase = wgn * 64;
  int arow = mbase + (l & 15);
  int koff = (l >> 4) * 8;
  f32x4 acc[4] = {};
  for (int kt = 0; kt < K / 32; ++kt) {
    bf16x8 a = *(const bf16x8*)(A + (size_t)arow * K + kt * 32 + koff);
#pragma unroll
    for (int n = 0; n < 4; ++n) {
      int col = nbase + n * 16 + (l & 15);
      bf16x8 bh = *(const bf16x8*)(Bhi + (size_t)col * K + kt * 32 + koff);
      bf16x8 bl = *(const bf16x8*)(Blo + (size_t)col * K + kt * 32 + koff);
      acc[n] = MFMA(a, bh, acc[n]);
      acc[n] = MFMA(a, bl, acc[n]);
    }
  }
#pragma unroll
  for (int n = 0; n < 4; ++n) {
    int col = nbase + n * 16 + (l & 15);
    float bv = bias[col];
#pragma unroll
    for (int r = 0; r < 4; ++r) {
      int row = mbase + (l >> 4) * 4 + r;
      int t = row >> 5, b = row & 31;
      y[((size_t)b * TT + t) * OO + col] = acc[n][r] + bv;
    }
  }
}

// ---------------- fused persistent scan ----------------
// 256 WGs = 4 clusters x 64 WGs: cid 0=L0fwd 1=L0bwd 2=L1fwd 3=L1bwd.
// Each WG: 32 packed gate-cols (8 hidden units); wave = (rowgrp, colgrp):
// colgrp cg owns 16 cols, rowgrp rg owns 16 batch rows. Weights held in
// VGPRs as MFMA B-frags for the whole kernel (no LDS at all).

static __device__ __forceinline__ void wait1(const unsigned* f, unsigned tgt) {
  const int l = threadIdx.x & 63;
  while (true) {
    unsigned v = __hip_atomic_load(f + l, __ATOMIC_RELAXED, __HIP_MEMORY_SCOPE_AGENT);
    if (__all((int)(v >= tgt))) break;
  }
  __threadfence();  // acquire: no stale L1 lines, no load hoisting above poll
}
static __device__ __forceinline__ void wait2(const unsigned* a, unsigned ta,
                                             const unsigned* b, unsigned tb) {
  const int l = threadIdx.x & 63;
  while (true) {
    unsigned va = __hip_atomic_load(a + l, __ATOMIC_RELAXED, __HIP_MEMORY_SCOPE_AGENT);
    unsigned vb = __hip_atomic_load(b + l, __ATOMIC_RELAXED, __HIP_MEMORY_SCOPE_AGENT);
    if (__all((int)((va >= ta) && (vb >= tb)))) break;
  }
  __threadfence();
}

__global__ void __launch_bounds__(256, 1) scan_fused(
    const unsigned short* __restrict__ W0hi, const unsigned short* __restrict__ W0lo,
    const unsigned short* __restrict__ Xhi, const unsigned short* __restrict__ Xlo,
    const unsigned short* __restrict__ Rhi, const unsigned short* __restrict__ Rlo,
    const float* __restrict__ g0x, const float* __restrict__ biasmp,
    unsigned short* __restrict__ h0, unsigned short* __restrict__ out1,
    float* __restrict__ gates, float* __restrict__ hn,
    unsigned int* __restrict__ flags) {
  const int bid = blockIdx.x;
  const int cid = bid >> 6;
  const int wg = bid & 63;
  const int dir = cid & 1;
  const int tid = threadIdx.x;
  const int l = tid & 63;
  const int wave = tid >> 6;
  const int cg = wave & 1;
  const int rg = wave >> 1;
  const int col = wg * 32 + cg * 16 + (l & 15);  // packed gate-col
  const int gate = col & 3;
  const int ug = col >> 2;                        // hidden unit 0..511
  const int kq = (l >> 4) * 8;                    // A/B frag k-offset
  const int q = l & 60;                           // gate-quad base lane
  const int arow = rg * 16 + (l & 15);            // A-operand row
  const int crow = rg * 16 + (l >> 4) * 4;        // C rows base
  const int srow = crow + (l & 3);                // this lane's h-store row
  unsigned int* myf = flags + cid * 64;
  unsigned short* hbase = h0 + (size_t)dir * TT * BB * HH;

  if (cid < 2) {
    // ---- layer 0: acc init from precomputed x-gates, one recurrent pass ----
    bf16x8 wr_h[16], wr_l[16];
    {
      const unsigned short* p1 = W0hi + (size_t)col * HH + kq;
      const unsigned short* p2 = W0lo + (size_t)col * HH + kq;
#pragma unroll
      for (int kt = 0; kt < 16; ++kt) {
        wr_h[kt] = *(const bf16x8*)(p1 + kt * 32);
        wr_l[kt] = *(const bf16x8*)(p2 + kt * 32);
      }
    }
    float cprev[4] = {0.f, 0.f, 0.f, 0.f};
    for (int t = 0; t < TT; ++t) {
      const int tin = dir ? (TT - 1 - t) : t;
      f32x4 acc;
      const float* gp = g0x + ((size_t)tin * BB + crow) * N4H + col;
#pragma unroll
      for (int r = 0; r < 4; ++r) acc[r] = gp[(size_t)r * N4H];
      if (t > 0) {
        wait1(myf, (unsigned)t);
        const unsigned short* ap = hbase + ((size_t)(t - 1) * BB + arow) * HH + kq;
#pragma unroll
        for (int kt = 0; kt < 16; ++kt) {
          bf16x8 a = *(const bf16x8*)(ap + kt * 32);
          acc = MFMA(a, wr_h[kt], acc);
          acc = MFMA(a, wr_l[kt], acc);
        }
      }
      float hsel = 0.f;
#pragma unroll
      for (int r = 0; r < 4; ++r) {
        float pre = acc[r];
        float own = (gate == 2) ? tanh_(pre) : sigm(pre);
        float iv = __shfl(own, q + 0, 64);
        float fv = __shfl(own, q + 1, 64);
        float gv = __shfl(own, q + 2, 64);
        float ov = __shfl(own, q + 3, 64);
        float cn = fv * cprev[r] + iv * gv;
        cprev[r] = cn;
        float hv = ov * tanh_(cn);
        if ((l & 3) == r) hsel = hv;
      }
      __hip_atomic_store(hbase + ((size_t)t * BB + srow) * HH + ug, f2bf(hsel),
                         __ATOMIC_RELAXED, __HIP_MEMORY_SCOPE_AGENT);
      __syncthreads();
      if (tid == 0)
        __hip_atomic_store(myf + wg, (unsigned)(t + 1), __ATOMIC_RELAXED,
                           __HIP_MEMORY_SCOPE_AGENT);
    }
  } else {
    // ---- layer 1: fused x-GEMM (from h0) + recurrent pass + outputs ----
    const unsigned* l0f = flags + (cid - 2) * 64;
    bf16x8 wx_h[16], wx_l[16], wr_h[16], wr_l[16];
    {
      const unsigned short* p1 = Xhi + (size_t)col * HH + kq;
      const unsigned short* p2 = Xlo + (size_t)col * HH + kq;
      const unsigned short* p3 = Rhi + (size_t)col * HH + kq;
      const unsigned short* p4 = Rlo + (size_t)col * HH + kq;
#pragma unroll
      for (int kt = 0; kt < 16; ++kt) {
        wx_h[kt] = *(const bf16x8*)(p1 + kt * 32);
        wx_l[kt] = *(const bf16x8*)(p2 + kt * 32);
        wr_h[kt] = *(const bf16x8*)(p3 + kt * 32);
        wr_l[kt] = *(const bf16x8*)(p4 + kt * 32);
      }
    }
    const float bias = biasmp[col];
    float cprev[4] = {0.f, 0.f, 0.f, 0.f};
    for (int t = 0; t < TT; ++t) {
      // one wait point: h0[t] ready (L0 flag t+1) AND own h1[t-1] ready
      wait2(l0f, (unsigned)(t + 1), myf, (unsigned)t);
      f32x4 accx = {}, accr = {};
      if (t > 0) {
        const unsigned short* rp =
            out1 + ((size_t)(t - 1) * BB + arow) * (2 * HH) + dir * HH + kq;
#pragma unroll
        for (int kt = 0; kt < 16; ++kt) {
          bf16x8 a = *(const bf16x8*)(rp + kt * 32);
          accr = MFMA(a, wr_h[kt], accr);
          accr = MFMA(a, wr_l[kt], accr);
        }
      }
      {
        const unsigned short* ap = hbase + ((size_t)t * BB + arow) * HH + kq;
#pragma unroll
        for (int kt = 0; kt < 16; ++kt) {
          bf16x8 a = *(const bf16x8*)(ap + kt * 32);
          accx = MFMA(a, wx_h[kt], accx);
          accx = MFMA(a, wx_l[kt], accx);
        }
      }
      float hsel = 0.f;
#pragma unroll
      for (int r = 0; r < 4; ++r) {
        float pre = accx[r] + accr[r] + bias;
        float own = (gate == 2) ? tanh_(pre) : sigm(pre);
        gates[(((size_t)t * 4 + gate) * BB + crow + r) * (2 * HH) + dir * HH + ug] = own;
        float iv = __shfl(own, q + 0, 64);
        float fv = __shfl(own, q + 1, 64);
        float gv = __shfl(own, q + 2, 64);
        float ov = __shfl(own, q + 3, 64);
        float cn = fv * cprev[r] + iv * gv;
        cprev[r] = cn;
        if (gate == 1)
          hn[((size_t)t * BB + crow + r) * (2 * HH) + dir * HH + ug] = cn;
        float hv = ov * tanh_(cn);
        if ((l & 3) == r) hsel = hv;
      }
      __hip_atomic_store(out1 + ((size_t)t * BB + srow) * (2 * HH) + dir * HH + ug,
                         f2bf(hsel), __ATOMIC_RELAXED, __HIP_MEMORY_SCOPE_AGENT);
      __syncthreads();
      if (tid == 0)
        __hip_atomic_store(myf + wg, (unsigned)(t + 1), __ATOMIC_RELAXED,
                           __HIP_MEMORY_SCOPE_AGENT);
    }
  }
}

// ---------------- host ----------------
extern "C" void kernel_launch(void* const* d_in, const int* in_sizes, int n_in,
                              void* d_out, int out_size, void* d_ws, size_t ws_size,
                              hipStream_t stream) {
  const float* inputs   = (const float*)d_in[0];
  const float* w_ih_in  = (const float*)d_in[1];
  const float* w_hh_in  = (const float*)d_in[2];
  const float* b_ih_in  = (const float*)d_in[3];
  const float* b_hh_in  = (const float*)d_in[4];
  const float* w_ih_mid = (const float*)d_in[5];
  const float* w_hh_mid = (const float*)d_in[6];
  const float* b_ih_mid = (const float*)d_in[7];
  const float* b_hh_mid = (const float*)d_in[8];
  const float* fc_w     = (const float*)d_in[9];
  const float* fc_b     = (const float*)d_in[10];

  char* p = (char*)d_ws;
  auto take = [&](size_t n) { char* q = p; p += (n + 255) & ~(size_t)255; return q; };
  unsigned short* xb        = (unsigned short*)take((size_t)16384 * II * 2);
  unsigned short* wihin_hi  = (unsigned short*)take((size_t)N4H * II * 2);
  unsigned short* wihin_lo  = (unsigned short*)take((size_t)N4H * II * 2);
  unsigned short* whhin_hi  = (unsigned short*)take((size_t)N4H * HH * 2);
  unsigned short* whhin_lo  = (unsigned short*)take((size_t)N4H * HH * 2);
  unsigned short* wihmid_hi = (unsigned short*)take((size_t)N4H * HH * 2);
  unsigned short* wihmid_lo = (unsigned short*)take((size_t)N4H * HH * 2);
  unsigned short* whhmid_hi = (unsigned short*)take((size_t)N4H * HH * 2);
  unsigned short* whhmid_lo = (unsigned short*)take((size_t)N4H * HH * 2);
  unsigned short* fchi      = (unsigned short*)take((size_t)OO * 2 * HH * 2);
  unsigned short* fclo      = (unsigned short*)take((size_t)OO * 2 * HH * 2);
  float* bias0p             = (float*)take((size_t)N4H * 4);
  float* biasmp             = (float*)take((size_t)N4H * 4);
  float* g0x                = (float*)take((size_t)16384 * N4H * 4);
  unsigned short* h0        = (unsigned short*)take((size_t)2 * TT * BB * HH * 2);
  unsigned short* out1      = (unsigned short*)take((size_t)TT * BB * 2 * HH * 2);
  unsigned int* flags       = (unsigned int*)take(4096);

  float* y_out     = (float*)d_out;
  float* gates_out = y_out + (size_t)BB * TT * OO;
  float* hn_out    = gates_out + (size_t)TT * 4 * BB * 2 * HH;

  hipMemsetAsync(flags, 0, 4096, stream);

  prep_w<<<256, 256, 0, stream>>>(w_ih_in, wihin_hi, wihin_lo, II, N4H, 1);
  prep_w<<<512, 256, 0, stream>>>(w_hh_in, whhin_hi, whhin_lo, HH, N4H, 1);
  prep_w<<<512, 256, 0, stream>>>(w_ih_mid, wihmid_hi, wihmid_lo, HH, N4H, 1);
  prep_w<<<512, 256, 0, stream>>>(w_hh_mid, whhmid_hi, whhmid_lo, HH, N4H, 1);
  prep_w<<<128, 256, 0, stream>>>(fc_w, fchi, fclo, 2 * HH, OO, 0);
  prep_bias<<<8, 256, 0, stream>>>(b_ih_in, b_hh_in, b_ih_mid, b_hh_mid, bias0p, biasmp);
  prep_x<<<2048, 256, 0, stream>>>(inputs, xb);
  gemm_g0<<<8192, 256, 0, stream>>>(xb, wihin_hi, wihin_lo, bias0p, g0x);
  scan_fused<<<256, 256, 0, stream>>>(whhin_hi, whhin_lo, wihmid_hi, wihmid_lo,
                                      whhmid_hi, whhmid_lo, g0x, biasmp, h0, out1,
                                      gates_out, hn_out, flags);
  gemm_fc<<<1024, 256, 0, stream>>>(out1, fchi, fclo, fc_b, y_out);
}

// Round 7
// 14010.695 us; speedup vs baseline: 1.0141x; 1.0141x over previous
//
#include <hip/hip_runtime.h>
#include <hip/hip_bf16.h>
#include <stdint.h>

#define TT 512
#define BB 32
#define II 256
#define HH 512
#define OO 256
#define N4H 2048
#define PADE 2048                      // 4KB pad per (dir,t) block: no cross-block prefetch
#define HBLKE (BB * HH + PADE)         // elems per t-block (h0 and each out1 dir-region)
#define TTHB ((size_t)TT * HBLKE)

typedef __attribute__((ext_vector_type(8))) short bf16x8;
typedef __attribute__((ext_vector_type(4))) float f32x4;

#define KEEP(x) asm volatile("" : "+v"(x))

static __device__ __forceinline__ f32x4 MFMA(bf16x8 a, bf16x8 b, f32x4 c) {
  return __builtin_amdgcn_mfma_f32_16x16x32_bf16(a, b, c, 0, 0, 0);
}
static __device__ __forceinline__ unsigned short f2bf(float x) {
  union { float f; unsigned u; } v; v.f = x;
  unsigned r = v.u + 0x7FFFu + ((v.u >> 16) & 1u);
  return (unsigned short)(r >> 16);
}
static __device__ __forceinline__ float bf2f(unsigned short b) {
  union { unsigned u; float f; } v; v.u = ((unsigned)b) << 16; return v.f;
}
static __device__ __forceinline__ float sigm(float x) {
  return 1.0f / (1.0f + __expf(-x));
}
static __device__ __forceinline__ float tanh_(float x) {
  return 1.0f - 2.0f / (1.0f + __expf(2.0f * x));
}

// ---------------- prep kernels ----------------

__global__ void prep_w(const float* __restrict__ src, unsigned short* __restrict__ hi,
                       unsigned short* __restrict__ lo, int K, int N, int packed) {
  int tid = blockIdx.x * 256 + threadIdx.x;
  int nch = K >> 3;
  if (tid >= N * nch) return;
  int c = tid / nch;
  int j = (tid - c * nch) << 3;
  int row = packed ? ((c & 3) * HH + (c >> 2)) : c;
  const float* s = src + (size_t)row * K + j;
  alignas(16) unsigned short h8[8];
  alignas(16) unsigned short l8[8];
#pragma unroll
  for (int e = 0; e < 8; ++e) {
    float v = s[e];
    unsigned short hb = f2bf(v);
    h8[e] = hb;
    l8[e] = f2bf(v - bf2f(hb));
  }
  *(uint4*)(hi + (size_t)c * K + j) = *(const uint4*)h8;
  *(uint4*)(lo + (size_t)c * K + j) = *(const uint4*)l8;
}

__global__ void prep_bias(const float* __restrict__ bi0, const float* __restrict__ bh0,
                          const float* __restrict__ bim, const float* __restrict__ bhm,
                          float* __restrict__ bias0p, float* __restrict__ biasmp) {
  int c = blockIdx.x * 256 + threadIdx.x;
  if (c >= N4H) return;
  int row = (c & 3) * HH + (c >> 2);
  bias0p[c] = bi0[row] + bh0[row];
  biasmp[c] = bim[row] + bhm[row];
}

__global__ void prep_x(const float* __restrict__ in, unsigned short* __restrict__ xb) {
  int tid = blockIdx.x * 256 + threadIdx.x;
  if (tid >= 16384 * 32) return;
  int row = tid >> 5, j = (tid & 31) << 3;
  int t = row >> 5, b = row & 31;
  const float* s = in + ((size_t)b * TT + t) * II + j;
  alignas(16) unsigned short o8[8];
#pragma unroll
  for (int e = 0; e < 8; ++e) o8[e] = f2bf(s[e]);
  *(uint4*)(xb + (size_t)row * II + j) = *(const uint4*)o8;
}

// ---------------- big GEMMs ----------------

__global__ __launch_bounds__(256) void gemm_g0(
    const unsigned short* __restrict__ A, const unsigned short* __restrict__ Bhi,
    const unsigned short* __restrict__ Blo, const float* __restrict__ biasp,
    float* __restrict__ out) {
  const int K = II;
  int wgm = blockIdx.x & 255;
  int wgn = blockIdx.x >> 8;
  int l = threadIdx.x & 63, wave = threadIdx.x >> 6;
  int mbase = wgm * 64 + wave * 16;
  int nbase = wgn * 64;
  int arow = mbase + (l & 15);
  int koff = (l >> 4) * 8;
  f32x4 acc[4] = {};
  for (int kt = 0; kt < K / 32; ++kt) {
    bf16x8 a = *(const bf16x8*)(A + (size_t)arow * K + kt * 32 + koff);
#pragma unroll
    for (int n = 0; n < 4; ++n) {
      int col = nbase + n * 16 + (l & 15);
      bf16x8 bh = *(const bf16x8*)(Bhi + (size_t)col * K + kt * 32 + koff);
      bf16x8 bl = *(const bf16x8*)(Blo + (size_t)col * K + kt * 32 + koff);
      acc[n] = MFMA(a, bh, acc[n]);
      acc[n] = MFMA(a, bl, acc[n]);
    }
  }
#pragma unroll
  for (int n = 0; n < 4; ++n) {
    int col = nbase + n * 16 + (l & 15);
    float bv = biasp[col];
#pragma unroll
    for (int r = 0; r < 4; ++r) {
      int row = mbase + (l >> 4) * 4 + r;
      out[(size_t)row * N4H + col] = acc[n][r] + bv;
    }
  }
}

// y = [out1_fwd | out1_bwd] @ fc_w^T + fc_b, reading the two padded dir regions
__global__ __launch_bounds__(256) void gemm_fc(
    const unsigned short* __restrict__ A, const unsigned short* __restrict__ Bhi,
    const unsigned short* __restrict__ Blo, const float* __restrict__ bias,
    float* __restrict__ y) {
  const int K = 2 * HH;
  int wgm = blockIdx.x & 255;
  int wgn = blockIdx.x >> 8;
  int l = threadIdx.x & 63, wave = threadIdx.x >> 6;
  int mbase = wgm * 64 + wave * 16;
  int nbase = wgn * 64;
  int arow = mbase + (l & 15);
  int koff = (l >> 4) * 8;
  int t0 = arow >> 5, b0 = arow & 31;
  const unsigned short* Af = A + (size_t)t0 * HBLKE + (size_t)b0 * HH;
  const unsigned short* Ab = Af + TTHB;
  f32x4 acc[4] = {};
#pragma unroll
  for (int kt = 0; kt < K / 32; ++kt) {
    const unsigned short* ap =
        (kt < 16) ? (Af + kt * 32 + koff) : (Ab + (kt - 16) * 32 + koff);
    bf16x8 a = *(const bf16x8*)ap;
#pragma unroll
    for (int n = 0; n < 4; ++n) {
      int col = nbase + n * 16 + (l & 15);
      bf16x8 bh = *(const bf16x8*)(Bhi + (size_t)col * K + kt * 32 + koff);
      bf16x8 bl = *(const bf16x8*)(Blo + (size_t)col * K + kt * 32 + koff);
      acc[n] = MFMA(a, bh, acc[n]);
      acc[n] = MFMA(a, bl, acc[n]);
    }
  }
#pragma unroll
  for (int n = 0; n < 4; ++n) {
    int col = nbase + n * 16 + (l & 15);
    float bv = bias[col];
#pragma unroll
    for (int r = 0; r < 4; ++r) {
      int row = mbase + (l >> 4) * 4 + r;
      int t = row >> 5, b = row & 31;
      y[((size_t)b * TT + t) * OO + col] = acc[n][r] + bv;
    }
  }
}

// ---------------- fused persistent scan ----------------
// 256 WGs = 4 clusters x 64 WGs: cid 0=L0fwd 1=L0bwd 2=L1fwd 3=L1bwd.
// Sync mechanism = R2 (proven): 16-bit agent atomic h-stores -> __syncthreads
// -> flag; consumer poll + __threadfence() (acquire inv) + plain loads.
// Weights pinned in VGPRs (KEEP). Per-(dir,t) blocks padded 4KB, dirs fully
// separated, so no stale adjacent-line pollution (hedge for dropping fence).

static __device__ __forceinline__ void wait1(const unsigned* f, unsigned tgt) {
  const int l = threadIdx.x & 63;
  while (true) {
    unsigned v = __hip_atomic_load(f + l, __ATOMIC_RELAXED, __HIP_MEMORY_SCOPE_AGENT);
    if (__all((int)(v >= tgt))) break;
    __builtin_amdgcn_s_sleep(1);
  }
  __threadfence();
}
static __device__ __forceinline__ void wait2(const unsigned* a, unsigned ta,
                                             const unsigned* b, unsigned tb) {
  const int l = threadIdx.x & 63;
  while (true) {
    unsigned va = __hip_atomic_load(a + l, __ATOMIC_RELAXED, __HIP_MEMORY_SCOPE_AGENT);
    unsigned vb = __hip_atomic_load(b + l, __ATOMIC_RELAXED, __HIP_MEMORY_SCOPE_AGENT);
    if (__all((int)((va >= ta) && (vb >= tb)))) break;
    __builtin_amdgcn_s_sleep(1);
  }
  __threadfence();
}

__global__ void __launch_bounds__(256, 1) scan_fused(
    const unsigned short* __restrict__ W0hi, const unsigned short* __restrict__ W0lo,
    const unsigned short* __restrict__ Xhi, const unsigned short* __restrict__ Xlo,
    const unsigned short* __restrict__ Rhi, const unsigned short* __restrict__ Rlo,
    const float* __restrict__ g0x, const float* __restrict__ biasmp,
    unsigned short* __restrict__ h0, unsigned short* __restrict__ out1,
    float* __restrict__ gates, float* __restrict__ hn,
    unsigned int* __restrict__ flags) {
  const int bid = blockIdx.x;
  const int cid = bid >> 6;
  const int wg = bid & 63;
  const int dir = cid & 1;
  const int tid = threadIdx.x;
  const int l = tid & 63;
  const int wave = tid >> 6;
  const int cg = wave & 1;
  const int rg = wave >> 1;
  const int col = wg * 32 + cg * 16 + (l & 15);  // packed gate-col
  const int gate = col & 3;
  const int ug = col >> 2;                        // hidden unit 0..511
  const int kq = (l >> 4) * 8;                    // frag k-offset
  const int q = l & 60;                           // gate-quad base lane
  const int arow = rg * 16 + (l & 15);            // A-operand row
  const int crow = rg * 16 + (l >> 4) * 4;        // C rows base
  const int srow = crow + (l & 3);                // this lane's h-store row
  unsigned int* myf = flags + cid * 64;
  unsigned short* hreg = h0 + (size_t)dir * TTHB;

  if (cid < 2) {
    // ---- layer 0 ----
    bf16x8 wr_h[16], wr_l[16];
    {
      const unsigned short* p1 = W0hi + (size_t)col * HH + kq;
      const unsigned short* p2 = W0lo + (size_t)col * HH + kq;
#pragma unroll
      for (int kt = 0; kt < 16; ++kt) {
        wr_h[kt] = *(const bf16x8*)(p1 + kt * 32);
        wr_l[kt] = *(const bf16x8*)(p2 + kt * 32);
      }
#pragma unroll
      for (int kt = 0; kt < 16; ++kt) { KEEP(wr_h[kt]); KEEP(wr_l[kt]); }
    }
    float cprev[4] = {0.f, 0.f, 0.f, 0.f};
    for (int t = 0; t < TT; ++t) {
      const int tin = dir ? (TT - 1 - t) : t;
      f32x4 acc;
      const float* gp = g0x + ((size_t)tin * BB + crow) * N4H + col;
#pragma unroll
      for (int r = 0; r < 4; ++r) acc[r] = gp[(size_t)r * N4H];
      if (t > 0) {
        wait1(myf, (unsigned)t);
        const unsigned short* ap =
            hreg + (size_t)(t - 1) * HBLKE + (size_t)arow * HH + kq;
#pragma unroll
        for (int kt = 0; kt < 16; ++kt) {
          bf16x8 a = *(const bf16x8*)(ap + kt * 32);
          acc = MFMA(a, wr_h[kt], acc);
          acc = MFMA(a, wr_l[kt], acc);
        }
      }
      float hsel = 0.f;
#pragma unroll
      for (int r = 0; r < 4; ++r) {
        float pre = acc[r];
        float own = (gate == 2) ? tanh_(pre) : sigm(pre);
        float iv = __shfl(own, q + 0, 64);
        float fv = __shfl(own, q + 1, 64);
        float gv = __shfl(own, q + 2, 64);
        float ov = __shfl(own, q + 3, 64);
        float cn = fv * cprev[r] + iv * gv;
        cprev[r] = cn;
        float hv = ov * tanh_(cn);
        if ((l & 3) == r) hsel = hv;
      }
      __hip_atomic_store(hreg + (size_t)t * HBLKE + (size_t)srow * HH + ug,
                         f2bf(hsel), __ATOMIC_RELAXED, __HIP_MEMORY_SCOPE_AGENT);
      __syncthreads();  // vmcnt drain: h visible before flag
      if (tid == 0)
        __hip_atomic_store(myf + wg, (unsigned)(t + 1), __ATOMIC_RELAXED,
                           __HIP_MEMORY_SCOPE_AGENT);
    }
  } else {
    // ---- layer 1 ----
    const unsigned* l0f = flags + (cid - 2) * 64;
    unsigned short* oreg = out1 + (size_t)dir * TTHB;
    bf16x8 wx_h[16], wx_l[16], wr_h[16], wr_l[16];
    {
      const unsigned short* p1 = Xhi + (size_t)col * HH + kq;
      const unsigned short* p2 = Xlo + (size_t)col * HH + kq;
      const unsigned short* p3 = Rhi + (size_t)col * HH + kq;
      const unsigned short* p4 = Rlo + (size_t)col * HH + kq;
#pragma unroll
      for (int kt = 0; kt < 16; ++kt) {
        wx_h[kt] = *(const bf16x8*)(p1 + kt * 32);
        wx_l[kt] = *(const bf16x8*)(p2 + kt * 32);
        wr_h[kt] = *(const bf16x8*)(p3 + kt * 32);
        wr_l[kt] = *(const bf16x8*)(p4 + kt * 32);
      }
#pragma unroll
      for (int kt = 0; kt < 16; ++kt) {
        KEEP(wx_h[kt]); KEEP(wx_l[kt]); KEEP(wr_h[kt]); KEEP(wr_l[kt]);
      }
    }
    const float bias = biasmp[col];
    float cprev[4] = {0.f, 0.f, 0.f, 0.f};
    for (int t = 0; t < TT; ++t) {
      // one wait point: h0[t] ready (L0 flag t+1) AND own h1[t-1] ready
      wait2(l0f, (unsigned)(t + 1), myf, (unsigned)t);
      f32x4 accx = {}, accr = {};
      if (t > 0) {
        const unsigned short* rp =
            oreg + (size_t)(t - 1) * HBLKE + (size_t)arow * HH + kq;
#pragma unroll
        for (int kt = 0; kt < 16; ++kt) {
          bf16x8 a = *(const bf16x8*)(rp + kt * 32);
          accr = MFMA(a, wr_h[kt], accr);
          accr = MFMA(a, wr_l[kt], accr);
        }
      }
      {
        const unsigned short* ap =
            hreg + (size_t)t * HBLKE + (size_t)arow * HH + kq;
#pragma unroll
        for (int kt = 0; kt < 16; ++kt) {
          bf16x8 a = *(const bf16x8*)(ap + kt * 32);
          accx = MFMA(a, wx_h[kt], accx);
          accx = MFMA(a, wx_l[kt], accx);
        }
      }
      float hsel = 0.f;
#pragma unroll
      for (int r = 0; r < 4; ++r) {
        float pre = accx[r] + accr[r] + bias;
        float own = (gate == 2) ? tanh_(pre) : sigm(pre);
        gates[(((size_t)t * 4 + gate) * BB + crow + r) * (2 * HH) + dir * HH + ug] = own;
        float iv = __shfl(own, q + 0, 64);
        float fv = __shfl(own, q + 1, 64);
        float gv = __shfl(own, q + 2, 64);
        float ov = __shfl(own, q + 3, 64);
        float cn = fv * cprev[r] + iv * gv;
        cprev[r] = cn;
        if (gate == 1)
          hn[((size_t)t * BB + crow + r) * (2 * HH) + dir * HH + ug] = cn;
        float hv = ov * tanh_(cn);
        if ((l & 3) == r) hsel = hv;
      }
      __hip_atomic_store(oreg + (size_t)t * HBLKE + (size_t)srow * HH + ug,
                         f2bf(hsel), __ATOMIC_RELAXED, __HIP_MEMORY_SCOPE_AGENT);
      __syncthreads();
      if (tid == 0)
        __hip_atomic_store(myf + wg, (unsigned)(t + 1), __ATOMIC_RELAXED,
                           __HIP_MEMORY_SCOPE_AGENT);
    }
  }
}

// ---------------- host ----------------
extern "C" void kernel_launch(void* const* d_in, const int* in_sizes, int n_in,
                              void* d_out, int out_size, void* d_ws, size_t ws_size,
                              hipStream_t stream) {
  const float* inputs   = (const float*)d_in[0];
  const float* w_ih_in  = (const float*)d_in[1];
  const float* w_hh_in  = (const float*)d_in[2];
  const float* b_ih_in  = (const float*)d_in[3];
  const float* b_hh_in  = (const float*)d_in[4];
  const float* w_ih_mid = (const float*)d_in[5];
  const float* w_hh_mid = (const float*)d_in[6];
  const float* b_ih_mid = (const float*)d_in[7];
  const float* b_hh_mid = (const float*)d_in[8];
  const float* fc_w     = (const float*)d_in[9];
  const float* fc_b     = (const float*)d_in[10];

  char* p = (char*)d_ws;
  auto take = [&](size_t n) { char* q = p; p += (n + 255) & ~(size_t)255; return q; };
  unsigned short* xb        = (unsigned short*)take((size_t)16384 * II * 2);
  unsigned short* wihin_hi  = (unsigned short*)take((size_t)N4H * II * 2);
  unsigned short* wihin_lo  = (unsigned short*)take((size_t)N4H * II * 2);
  unsigned short* whhin_hi  = (unsigned short*)take((size_t)N4H * HH * 2);
  unsigned short* whhin_lo  = (unsigned short*)take((size_t)N4H * HH * 2);
  unsigned short* wihmid_hi = (unsigned short*)take((size_t)N4H * HH * 2);
  unsigned short* wihmid_lo = (unsigned short*)take((size_t)N4H * HH * 2);
  unsigned short* whhmid_hi = (unsigned short*)take((size_t)N4H * HH * 2);
  unsigned short* whhmid_lo = (unsigned short*)take((size_t)N4H * HH * 2);
  unsigned short* fchi      = (unsigned short*)take((size_t)OO * 2 * HH * 2);
  unsigned short* fclo      = (unsigned short*)take((size_t)OO * 2 * HH * 2);
  float* bias0p             = (float*)take((size_t)N4H * 4);
  float* biasmp             = (float*)take((size_t)N4H * 4);
  float* g0x                = (float*)take((size_t)16384 * N4H * 4);
  unsigned short* h0        = (unsigned short*)take((size_t)2 * TTHB * 2);
  unsigned short* out1      = (unsigned short*)take((size_t)2 * TTHB * 2);
  unsigned int* flags       = (unsigned int*)take(4096);

  float* y_out     = (float*)d_out;
  float* gates_out = y_out + (size_t)BB * TT * OO;
  float* hn_out    = gates_out + (size_t)TT * 4 * BB * 2 * HH;

  hipMemsetAsync(flags, 0, 4096, stream);

  prep_w<<<256, 256, 0, stream>>>(w_ih_in, wihin_hi, wihin_lo, II, N4H, 1);
  prep_w<<<512, 256, 0, stream>>>(w_hh_in, whhin_hi, whhin_lo, HH, N4H, 1);
  prep_w<<<512, 256, 0, stream>>>(w_ih_mid, wihmid_hi, wihmid_lo, HH, N4H, 1);
  prep_w<<<512, 256, 0, stream>>>(w_hh_mid, whhmid_hi, whhmid_lo, HH, N4H, 1);
  prep_w<<<128, 256, 0, stream>>>(fc_w, fchi, fclo, 2 * HH, OO, 0);
  prep_bias<<<8, 256, 0, stream>>>(b_ih_in, b_hh_in, b_ih_mid, b_hh_mid, bias0p, biasmp);
  prep_x<<<2048, 256, 0, stream>>>(inputs, xb);
  gemm_g0<<<8192, 256, 0, stream>>>(xb, wihin_hi, wihin_lo, bias0p, g0x);
  scan_fused<<<256, 256, 0, stream>>>(whhin_hi, whhin_lo, wihmid_hi, wihmid_lo,
                                      whhmid_hi, whhmid_lo, g0x, biasmp, h0, out1,
                                      gates_out, hn_out, flags);
  gemm_fc<<<1024, 256, 0, stream>>>(out1, fchi, fclo, fc_b, y_out);
}